// Round 2
// baseline (661.771 us; speedup 1.0000x reference)
//
#include <hip/hip_runtime.h>
#include <hip/hip_fp16.h>

#define N_NODES 100000
#define N_EDGES 1600000
#define BN_EPS 1e-5f
#define NBLK_E 6250      /* N_EDGES / 256 exact */
#define NBLK_G 3125      /* N_NODES / 32 exact */
#define NBLK_N 391       /* ceil(N_NODES/256) */
#define NBINS 391        /* buckets of 256 nodes */
#define BCAP 4608        /* entries per bucket (lambda=4096, +8 sigma) */
#define PT 4096          /* partition tile (edges per block) */
#define NPART 391        /* ceil(N_EDGES/PT) */
#define OVF_CAP 32768
#define A18 262144.0f
#define A18_INV 3.814697265625e-6f   /* 2^-18 */
typedef unsigned long long ull;
typedef unsigned int uint;

// bucket entry = local_d(8) | edge_idx(21) | src(17) | attr_q18(18)
// csr2 entry (after finalize) = attr_q18(high32) | src(low32)
// csr2 entry (after nrm blocks of gemm_l0_nrm) = f32(attr*dinv[src]) | src

// ---------------- init
__global__ void init_kernel(int* gcnt, int* win, uint* zbitmap, int* flags, float* bnacc) {
    int v = blockIdx.x * blockDim.x + threadIdx.x;
    if (v < N_NODES) win[v] = -1;
    if (v < NBINS) gcnt[v] = 0;
    if (v < 3125) zbitmap[v] = 0;
    if (v < 2) flags[v] = 0;          // [0]=zero-indeg-any  [1]=ovf_cnt
    if (v < 256) bnacc[v] = 0.0f;     // [2 layers][sum64|sq64]
}

// ---------------- partition (LDS-staged counting sort into 391 buckets) + fused h0 GEMM
__launch_bounds__(256)
__global__ void partition_gemm(const int* __restrict__ src, const int* __restrict__ dst,
                               const float* __restrict__ attr,
                               ull* __restrict__ bucket, int* __restrict__ gcnt,
                               int* __restrict__ flags, int* __restrict__ ovf_b,
                               ull* __restrict__ ovf_e,
                               const float* __restrict__ x, const float* __restrict__ lin_W,
                               const float* __restrict__ lin_b, float* __restrict__ h0) {
    __shared__ ull ent[PT];               // 32 KB
    __shared__ unsigned short ebin[PT];   // 8 KB
    __shared__ int hist[NBINS];
    __shared__ int cur[NBINS];
    __shared__ int gdel[NBINS];
    __shared__ int sc[512];
    int t = threadIdx.x;
    if (blockIdx.x < NPART) {
        int e0 = blockIdx.x * PT;
        int n = N_EDGES - e0; if (n > PT) n = PT;
        for (int b = t; b < NBINS; b += 256) hist[b] = 0;
        __syncthreads();
        for (int k = t; k < n; k += 256) atomicAdd(&hist[dst[e0 + k] >> 8], 1);
        __syncthreads();
        sc[t] = (t < NBINS) ? hist[t] : 0;
        sc[t + 256] = (t + 256 < NBINS) ? hist[t + 256] : 0;
        __syncthreads();
        for (int off = 1; off < 512; off <<= 1) {
            int a0 = sc[t] + ((t >= off) ? sc[t - off] : 0);
            int a1 = sc[t + 256] + sc[t + 256 - off];
            __syncthreads();
            sc[t] = a0; sc[t + 256] = a1;
            __syncthreads();
        }
        for (int b = t; b < NBINS; b += 256) {
            int lb = sc[b] - hist[b];
            cur[b] = lb;
            int gb = atomicAdd(&gcnt[b], hist[b]);
            gdel[b] = gb - lb;
        }
        __syncthreads();
        for (int k = t; k < n; k += 256) {
            int i = e0 + k;
            int d = dst[i];
            uint aq = (uint)(attr[i] * A18); if (aq > 0x3FFFFu) aq = 0x3FFFFu;
            int bin = d >> 8;
            ull e = ((ull)(d & 255) << 56) | ((ull)i << 35) | ((ull)src[i] << 18) | aq;
            int p = atomicAdd(&cur[bin], 1);
            ent[p] = e;
            ebin[p] = (unsigned short)bin;
        }
        __syncthreads();
        for (int k = t; k < n; k += 256) {
            int b = ebin[k];
            int off = k + gdel[b];
            if (off < BCAP) bucket[(size_t)b * BCAP + off] = ent[k];
            else {
                int q = atomicAdd(&flags[1], 1);
                if (q < OVF_CAP) { ovf_b[q] = b; ovf_e[q] = ent[k]; }
            }
        }
        return;
    }
    // ---- fused GEMM blocks: h0 = x @ lin_W + lin_b
    float* xs = (float*)ent;
    int lane = t & 63, w = t >> 6;
    int base = (blockIdx.x - NPART) * 32;
    const float4* Xv = (const float4*)(x + (size_t)base * 64);
    float4* xsv = (float4*)xs;
    xsv[t] = Xv[t];
    xsv[t + 256] = Xv[t + 256];
    float wc[64];
    #pragma unroll
    for (int k = 0; k < 64; ++k) wc[k] = lin_W[k * 64 + lane];
    __syncthreads();
    float bval = lin_b[lane];
    for (int rr = 0; rr < 8; ++rr) {
        int rl = w * 8 + rr;
        float acc = bval;
        #pragma unroll
        for (int k = 0; k < 64; ++k) acc = fmaf(xs[rl * 64 + k], wc[k], acc);
        h0[(size_t)(base + rl) * 64 + lane] = acc;
    }
}

// ---------------- finalize+reorder: node-sort entries -> csr2 (coalesced),
// per-node start/len, deg->dinv, last-write-winner attr, zero-indeg marks.
__launch_bounds__(256)
__global__ void finalize_reorder(const ull* __restrict__ bucket, const int* __restrict__ gcnt,
                                 const int* __restrict__ ovf_b, const ull* __restrict__ ovf_e,
                                 int* __restrict__ flags, uint* __restrict__ zbitmap,
                                 float* __restrict__ dinv, float* __restrict__ wa,
                                 ull* __restrict__ csr2, int* __restrict__ startv,
                                 int* __restrict__ lenv) {
    __shared__ ull ent[BCAP];        // 36.8 KB
    __shared__ int cnt[256];
    __shared__ int sc[256];
    __shared__ int cur[256];
    __shared__ int cbase[257];
    int t = threadIdx.x, b = blockIdx.x;
    int len = gcnt[b], blen = len < BCAP ? len : BCAP;
    const ull* bb = bucket + (size_t)b * BCAP;
    cnt[t] = 0;
    __syncthreads();
    ull r[18];
    #pragma unroll
    for (int k = 0; k < 18; ++k) {
        int j = k * 256 + t;
        r[k] = 0;
        if (j < blen) {
            ull e = bb[j];
            r[k] = e;
            atomicAdd(&cnt[(int)(e >> 56)], 1);
        }
    }
    __syncthreads();
    sc[t] = cnt[t];
    __syncthreads();
    for (int off = 1; off < 256; off <<= 1) {
        int a = sc[t] + ((t >= off) ? sc[t - off] : 0);
        __syncthreads();
        sc[t] = a;
        __syncthreads();
    }
    cbase[t + 1] = sc[t];
    if (t == 0) cbase[0] = 0;
    cur[t] = sc[t] - cnt[t];
    __syncthreads();
    #pragma unroll
    for (int k = 0; k < 18; ++k) {
        int j = k * 256 + t;
        if (j < blen) {
            ull e = r[k];
            int p = atomicAdd(&cur[(int)(e >> 56)], 1);
            ent[p] = e;
        }
    }
    __syncthreads();
    size_t base = (size_t)b * BCAP;
    for (int k = t; k < blen; k += 256) {
        ull e = ent[k];
        csr2[base + k] = (((ull)(e & 0x3FFFFull)) << 32) | ((e >> 18) & 0x1FFFFull);
    }
    int j0 = cbase[t], j1 = cbase[t + 1];
    float sum = 0.0f; uint winx = 0, wat = 0;
    for (int j = j0; j < j1; ++j) {
        ull e = ent[j];
        uint aq = (uint)(e & 0x3FFFFull);
        sum += (float)aq * A18_INV;
        uint ei = (uint)((e >> 35) & 0x1FFFFFull) + 1u;
        if (ei > winx) { winx = ei; wat = aq; }
    }
    if (len > BCAP) {                      // overflow (practically never)
        int oc = flags[1]; if (oc > OVF_CAP) oc = OVF_CAP;
        for (int q = 0; q < oc; ++q) {
            if (ovf_b[q] != b) continue;
            ull e = ovf_e[q];
            if ((int)(e >> 56) != t) continue;
            uint aq = (uint)(e & 0x3FFFFull);
            sum += (float)aq * A18_INV;
            uint ei = (uint)((e >> 35) & 0x1FFFFFull) + 1u;
            if (ei > winx) { winx = ei; wat = aq; }
        }
    }
    int v = b * 256 + t;
    if (v < N_NODES) {
        dinv[v] = rsqrtf(1.0f + sum);
        startv[v] = (int)(base + j0);
        lenv[v] = j1 - j0;
        if (winx > 0) {
            wa[v] = (float)wat * A18_INV;
        } else {
            wa[v] = -1.0f;
            atomicOr(&zbitmap[v >> 5], 1u << (v & 31));
            flags[0] = 1;
        }
    }
}

// ---------------- fixup: src-side winner for zero-in-degree nodes (early-exit)
__global__ void fixup_scan(const int* __restrict__ src, const int* __restrict__ flags,
                           const uint* __restrict__ zbitmap, int* __restrict__ win) {
    if (flags[0] == 0) return;
    int i = blockIdx.x * 256 + threadIdx.x;
    int s = src[i];
    if ((zbitmap[s >> 5] >> (s & 31)) & 1u) atomicMax(&win[s], i);
}

__global__ void fixup_apply(const int* __restrict__ flags, const uint* __restrict__ zbitmap,
                            const int* __restrict__ win, const float* __restrict__ attr,
                            float* __restrict__ wa) {
    if (flags[0] == 0) return;
    int v = blockIdx.x * 256 + threadIdx.x;
    if (v >= N_NODES) return;
    if (((zbitmap[v >> 5] >> (v & 31)) & 1u) && win[v] >= 0) wa[v] = attr[win[v]];
}

// ---------------- layer-0 GEMM + fused nrm-precompute blocks
// nrm blocks: csr2 entry (aq<<32|src) -> (f32(aq*dinv[src])<<32|src)
__launch_bounds__(256)
__global__ void gemm_l0_nrm(const float* __restrict__ h0, const float* __restrict__ W,
                            const float* __restrict__ wa, const float* __restrict__ ew,
                            const float* __restrict__ eb, __half* __restrict__ xw16,
                            ull* __restrict__ csr2, const int* __restrict__ gcnt,
                            const float* __restrict__ dinv) {
    __shared__ float xs[2048];
    int t = threadIdx.x;
    if (blockIdx.x < NBINS) {
        int b = blockIdx.x;
        int len = gcnt[b], blen = len < BCAP ? len : BCAP;
        ull* c = csr2 + (size_t)b * BCAP;
        for (int k = t; k < blen; k += 256) {
            ull pk = c[k];
            uint s = (uint)pk;
            float np = (float)(uint)(pk >> 32) * A18_INV * dinv[s];
            c[k] = ((ull)__float_as_uint(np) << 32) | s;
        }
        return;
    }
    int lane = t & 63, w = t >> 6;
    int base = (blockIdx.x - NBINS) * 32;
    const float4* Hv = (const float4*)(h0 + (size_t)base * 64);
    #pragma unroll
    for (int q = 0; q < 2; ++q) {
        int idx = t + q * 256;
        int rl = idx >> 4, f0 = (idx & 15) * 4;
        float4 v = Hv[idx];
        float wav = wa[base + rl];
        if (wav >= 0.0f) {
            v.x = fmaxf(fmaf(wav, ew[f0 + 0], v.x + eb[f0 + 0]), 0.0f);
            v.y = fmaxf(fmaf(wav, ew[f0 + 1], v.y + eb[f0 + 1]), 0.0f);
            v.z = fmaxf(fmaf(wav, ew[f0 + 2], v.z + eb[f0 + 2]), 0.0f);
            v.w = fmaxf(fmaf(wav, ew[f0 + 3], v.w + eb[f0 + 3]), 0.0f);
        }
        ((float4*)xs)[idx] = v;
    }
    float wc[64];
    #pragma unroll
    for (int k = 0; k < 64; ++k) wc[k] = W[k * 64 + lane];
    __syncthreads();
    for (int rr = 0; rr < 8; ++rr) {
        int rl = w * 8 + rr;
        float acc = 0.0f;
        #pragma unroll
        for (int k = 0; k < 64; ++k) acc = fmaf(xs[rl * 64 + k], wc[k], acc);
        xw16[(size_t)(base + rl) * 64 + lane] = __float2half(acc);
    }
}

// ---------------- layer-1 GEMM: stage agg0 + BN0 + relu, write out[:,0:64], fp16 xw
__launch_bounds__(256)
__global__ void gemm_l1(const float* __restrict__ agg, const float* __restrict__ bnacc,
                        const float* __restrict__ gamma, const float* __restrict__ beta,
                        const float* __restrict__ W, float* __restrict__ out,
                        __half* __restrict__ xw16) {
    __shared__ float xs[2048];
    int t = threadIdx.x, lane = t & 63, w = t >> 6;
    int base = blockIdx.x * 32;
    const float4* Av = (const float4*)(agg + (size_t)base * 64);
    const float invN = 1.0f / (float)N_NODES;
    #pragma unroll
    for (int q = 0; q < 2; ++q) {
        int idx = t + q * 256;
        int rl = idx >> 4, f0 = (idx & 15) * 4;
        float4 v = Av[idx];
        float vv[4] = {v.x, v.y, v.z, v.w};
        #pragma unroll
        for (int c = 0; c < 4; ++c) {
            int f = f0 + c;
            float mean = bnacc[f] * invN;
            float var = bnacc[64 + f] * invN - mean * mean;
            float scl = gamma[f] * rsqrtf(var + BN_EPS);
            float bs = beta[f] - mean * scl;
            vv[c] = fmaxf(fmaf(vv[c], scl, bs), 0.0f);
        }
        float4 r = {vv[0], vv[1], vv[2], vv[3]};
        ((float4*)xs)[idx] = r;
        *(float4*)(out + (size_t)(base + rl) * 128 + f0) = r;   // out[:, 0:64]
    }
    float wc[64];
    #pragma unroll
    for (int k = 0; k < 64; ++k) wc[k] = W[k * 64 + lane];
    __syncthreads();
    for (int rr = 0; rr < 8; ++rr) {
        int rl = w * 8 + rr;
        float acc = 0.0f;
        #pragma unroll
        for (int k = 0; k < 64; ++k) acc = fmaf(xs[rl * 64 + k], wc[k], acc);
        xw16[(size_t)(base + rl) * 64 + lane] = __float2half(acc);
    }
}

// ---------------- gather v5 ("gather16"): 4 nodes per wave; lane=(ng:2|fl:4);
// 8B/lane row loads (float2 = 4 halves); CSR chunks of 16/node, FULLY unrolled
// with all 16 row loads in flight (32 VGPRs of payload); zero-padded tails
// (pk=0 -> norm 0, reads hot row 0); next-chunk csr2 prefetch.
// __launch_bounds__(256,2) raises the VGPR budget to 256 so the scheduler does
// NOT clamp to ~40 VGPR and serialize the loads (R1 failure mode).
// 6250 blocks * 16 nodes = 100000 exact.
__launch_bounds__(256, 2)
__global__ void gather16(const __half* __restrict__ xw16, const ull* __restrict__ csr2,
                         const int* __restrict__ startv, const int* __restrict__ lenv,
                         const float* __restrict__ dinv, const int* __restrict__ gcnt,
                         const int* __restrict__ flags, const int* __restrict__ ovf_b,
                         const ull* __restrict__ ovf_e,
                         const float* __restrict__ convb, float* __restrict__ agg,
                         float* __restrict__ bnacc) {
    __shared__ float reds[4][64];
    __shared__ float redq[4][64];
    int t = threadIdx.x, lane = t & 63, w = t >> 6;
    int ng = lane >> 4, fl = lane & 15, f0 = fl * 4, ngb = ng << 4;
    int v = blockIdx.x * 16 + w * 4 + ng;            // < 100000 always
    float dv = dinv[v];
    int sb = startv[v], ln = lenv[v];
    // self-loop term: w2 * xw[v]
    float2 raw = *(const float2*)(xw16 + (size_t)v * 64 + f0);
    float2 xv01 = __half22float2(*(__half2*)&raw.x);
    float2 xv23 = __half22float2(*(__half2*)&raw.y);
    float w2 = dv * dv;
    float a0 = w2 * xv01.x, a1 = w2 * xv01.y, a2 = w2 * xv23.x, a3 = w2 * xv23.y;
    float b0 = 0.f, b1 = 0.f, b2 = 0.f, b3 = 0.f;
    // first chunk's entries (zero-padded beyond ln)
    ull pk = (fl < ln) ? csr2[sb + fl] : 0ull;
    for (int c0 = 0; c0 < ln; c0 += 16) {
        ull pkc = pk;
        int rem = ln - c0 - 16;
        pk = (fl < rem) ? csr2[sb + c0 + 16 + fl] : 0ull;   // prefetch next chunk
        float nr[16];
        float2 rw[16];
        #pragma unroll
        for (int j = 0; j < 16; ++j) {
            ull pj = __shfl(pkc, ngb + j, 64);
            nr[j] = __uint_as_float((uint)(pj >> 32)) * dv;
            rw[j] = *(const float2*)(xw16 + (size_t)(uint)pj * 64 + f0);
        }
        #pragma unroll
        for (int j = 0; j < 16; j += 2) {
            float2 xA01 = __half22float2(*(__half2*)&rw[j].x);
            float2 xA23 = __half22float2(*(__half2*)&rw[j].y);
            float2 xB01 = __half22float2(*(__half2*)&rw[j + 1].x);
            float2 xB23 = __half22float2(*(__half2*)&rw[j + 1].y);
            a0 = fmaf(nr[j], xA01.x, a0); a1 = fmaf(nr[j], xA01.y, a1);
            a2 = fmaf(nr[j], xA23.x, a2); a3 = fmaf(nr[j], xA23.y, a3);
            b0 = fmaf(nr[j + 1], xB01.x, b0); b1 = fmaf(nr[j + 1], xB01.y, b1);
            b2 = fmaf(nr[j + 1], xB23.x, b2); b3 = fmaf(nr[j + 1], xB23.y, b3);
        }
    }
    float t0 = a0 + b0, t1 = a1 + b1, t2 = a2 + b2, t3 = a3 + b3;
    int ovfn = flags[1];
    if (ovfn > 0 && gcnt[v >> 8] > BCAP) {     // practically never
        int oc = ovfn; if (oc > OVF_CAP) oc = OVF_CAP;
        int ld = v & 255, b = v >> 8;
        for (int q = 0; q < oc; ++q) {
            if (ovf_b[q] != b) continue;
            ull e = ovf_e[q];
            if ((int)(e >> 56) != ld) continue;
            uint s = (uint)((e >> 18) & 0x1FFFFull);
            float nrx = (float)(uint)(e & 0x3FFFFull) * A18_INV * dinv[s] * dv;
            float2 rr = *(const float2*)(xw16 + (size_t)s * 64 + f0);
            float2 x01 = __half22float2(*(__half2*)&rr.x);
            float2 x23 = __half22float2(*(__half2*)&rr.y);
            t0 = fmaf(nrx, x01.x, t0); t1 = fmaf(nrx, x01.y, t1);
            t2 = fmaf(nrx, x23.x, t2); t3 = fmaf(nrx, x23.y, t3);
        }
    }
    // + conv_b, store agg, accumulate BN stats
    float4 cb = *(const float4*)(convb + f0);
    t0 += cb.x; t1 += cb.y; t2 += cb.z; t3 += cb.w;
    *(float4*)(agg + (size_t)v * 64 + f0) = make_float4(t0, t1, t2, t3);
    float s0 = t0, s1 = t1, s2 = t2, s3 = t3;
    float q0 = t0 * t0, q1 = t1 * t1, q2 = t2 * t2, q3 = t3 * t3;
    // reduce across the 4 node-groups (lanes fl, 16+fl, 32+fl, 48+fl)
    s0 += __shfl_xor(s0, 16, 64); s0 += __shfl_xor(s0, 32, 64);
    s1 += __shfl_xor(s1, 16, 64); s1 += __shfl_xor(s1, 32, 64);
    s2 += __shfl_xor(s2, 16, 64); s2 += __shfl_xor(s2, 32, 64);
    s3 += __shfl_xor(s3, 16, 64); s3 += __shfl_xor(s3, 32, 64);
    q0 += __shfl_xor(q0, 16, 64); q0 += __shfl_xor(q0, 32, 64);
    q1 += __shfl_xor(q1, 16, 64); q1 += __shfl_xor(q1, 32, 64);
    q2 += __shfl_xor(q2, 16, 64); q2 += __shfl_xor(q2, 32, 64);
    q3 += __shfl_xor(q3, 16, 64); q3 += __shfl_xor(q3, 32, 64);
    if (ng == 0) {
        reds[w][f0] = s0; reds[w][f0 + 1] = s1; reds[w][f0 + 2] = s2; reds[w][f0 + 3] = s3;
        redq[w][f0] = q0; redq[w][f0 + 1] = q1; redq[w][f0 + 2] = q2; redq[w][f0 + 3] = q3;
    }
    __syncthreads();
    if (t < 64) {
        float ss = reds[0][t] + reds[1][t] + reds[2][t] + reds[3][t];
        float qq = redq[0][t] + redq[1][t] + redq[2][t] + redq[3][t];
        atomicAdd(&bnacc[t], ss);
        atomicAdd(&bnacc[64 + t], qq);
    }
}

// ---------------- final BN apply: out[:, 64:128]
__launch_bounds__(256)
__global__ void bn_final(const float* __restrict__ agg, const float* __restrict__ bnacc,
                         const float* __restrict__ gamma, const float* __restrict__ beta,
                         float* __restrict__ out) {
    int idx = blockIdx.x * 256 + threadIdx.x;
    int c = idx & 63, v = idx >> 6;
    const float invN = 1.0f / (float)N_NODES;
    float mean = bnacc[c] * invN;
    float var = bnacc[64 + c] * invN - mean * mean;
    float scl = gamma[c] * rsqrtf(var + BN_EPS);
    float bs = beta[c] - mean * scl;
    out[(size_t)v * 128 + 64 + c] = fmaf(agg[idx], scl, bs);
}

extern "C" void kernel_launch(void* const* d_in, const int* in_sizes, int n_in,
                              void* d_out, int out_size, void* d_ws, size_t ws_size,
                              hipStream_t stream) {
    const float* x      = (const float*)d_in[0];
    const int*   eidx   = (const int*)d_in[1];
    const float* attr   = (const float*)d_in[2];
    const float* lin_W  = (const float*)d_in[3];
    const float* lin_b  = (const float*)d_in[4];
    const float* eenc_w = (const float*)d_in[5];
    const float* eenc_b = (const float*)d_in[6];
    const float* conv_W = (const float*)d_in[7];
    const float* conv_b = (const float*)d_in[8];
    const float* gamma  = (const float*)d_in[9];
    const float* beta   = (const float*)d_in[10];
    float* out = (float*)d_out;

    const int* src = eidx;
    const int* dst = eidx + N_EDGES;

    // workspace carve (~70 MB)
    char* p = (char*)d_ws;
    ull* bucket = (ull*)p;   p += (size_t)NBINS * BCAP * 8;    // 14.4 MB
    ull* csr2   = (ull*)p;   p += (size_t)NBINS * BCAP * 8;    // 14.4 MB
    ull* ovf_e  = (ull*)p;   p += (size_t)OVF_CAP * 8;
    float* h0   = (float*)p; p += (size_t)N_NODES * 64 * 4;    // 25.6 MB (aliased: agg)
    __half* xw16 = (__half*)p; p += (size_t)N_NODES * 64 * 2;  // 12.8 MB
    float* dinv = (float*)p; p += (size_t)N_NODES * 4;
    float* wa   = (float*)p; p += (size_t)N_NODES * 4;
    int* win    = (int*)p;   p += (size_t)N_NODES * 4;
    int* startv = (int*)p;   p += (size_t)N_NODES * 4;
    int* lenv   = (int*)p;   p += (size_t)N_NODES * 4;
    int* ovf_b  = (int*)p;   p += (size_t)OVF_CAP * 4;
    int* gcnt   = (int*)p;   p += (NBINS + 1) * 4 + 20;
    uint* zbitmap = (uint*)p; p += 3125 * 4 + 12;
    int* flags  = (int*)p;   p += 64;
    float* bnacc = (float*)p; p += 256 * 4;                    // [2][128]
    float* agg = h0;   // h0 dead after gemm_l0_nrm

    init_kernel<<<NBLK_N, 256, 0, stream>>>(gcnt, win, zbitmap, flags, bnacc);
    partition_gemm<<<NPART + NBLK_G, 256, 0, stream>>>(src, dst, attr, bucket, gcnt,
                                                       flags, ovf_b, ovf_e,
                                                       x, lin_W, lin_b, h0);
    finalize_reorder<<<NBINS, 256, 0, stream>>>(bucket, gcnt, ovf_b, ovf_e,
                                                flags, zbitmap, dinv, wa,
                                                csr2, startv, lenv);
    fixup_scan<<<NBLK_E, 256, 0, stream>>>(src, flags, zbitmap, win);
    fixup_apply<<<NBLK_N, 256, 0, stream>>>(flags, zbitmap, win, attr, wa);

    gemm_l0_nrm<<<NBINS + NBLK_G, 256, 0, stream>>>(h0, conv_W, wa, eenc_w, eenc_b,
                                                    xw16, csr2, gcnt, dinv);
    gather16<<<6250, 256, 0, stream>>>(xw16, csr2, startv, lenv, dinv, gcnt,
                                       flags, ovf_b, ovf_e, conv_b, agg, bnacc);
    gemm_l1<<<NBLK_G, 256, 0, stream>>>(agg, bnacc, gamma, beta,
                                        conv_W + 64 * 64, out, xw16);
    gather16<<<6250, 256, 0, stream>>>(xw16, csr2, startv, lenv, dinv, gcnt,
                                       flags, ovf_b, ovf_e, conv_b + 64, agg, bnacc + 128);
    bn_final<<<25000, 256, 0, stream>>>(agg, bnacc + 128, gamma + 64, beta + 64, out);
}

// Round 3
// 659.978 us; speedup vs baseline: 1.0027x; 1.0027x over previous
//
#include <hip/hip_runtime.h>
#include <hip/hip_fp16.h>

#define N_NODES 100000
#define N_EDGES 1600000
#define BN_EPS 1e-5f
#define NBLK_E 6250      /* N_EDGES / 256 exact */
#define NBLK_G 3125      /* N_NODES / 32 exact */
#define NBLK_N 391       /* ceil(N_NODES/256) */
#define NBINS 391        /* buckets of 256 nodes */
#define BCAP 4608        /* entries per bucket (lambda=4096, +8 sigma) */
#define PT 4096          /* partition tile (edges per block) */
#define NPART 391        /* ceil(N_EDGES/PT) */
#define OVF_CAP 32768
#define A18 262144.0f
#define A18_INV 3.814697265625e-6f   /* 2^-18 */
typedef unsigned long long ull;
typedef unsigned int uint;
typedef unsigned int uint2v __attribute__((ext_vector_type(2)));

// bucket entry = local_d(8) | edge_idx(21) | src(17) | attr_q18(18)
// csr2 entry (after finalize) = attr_q18(high32) | src(low32)
// csr2 entry (after nrm blocks of gemm_l0_nrm) = f32(attr*dinv[src]) | src

// ---------------- init
__global__ void init_kernel(int* gcnt, int* win, uint* zbitmap, int* flags, float* bnacc) {
    int v = blockIdx.x * blockDim.x + threadIdx.x;
    if (v < N_NODES) win[v] = -1;
    if (v < NBINS) gcnt[v] = 0;
    if (v < 3125) zbitmap[v] = 0;
    if (v < 2) flags[v] = 0;          // [0]=zero-indeg-any  [1]=ovf_cnt
    if (v < 256) bnacc[v] = 0.0f;     // [2 layers][sum64|sq64]
}

// ---------------- partition (LDS-staged counting sort into 391 buckets) + fused h0 GEMM
__launch_bounds__(256)
__global__ void partition_gemm(const int* __restrict__ src, const int* __restrict__ dst,
                               const float* __restrict__ attr,
                               ull* __restrict__ bucket, int* __restrict__ gcnt,
                               int* __restrict__ flags, int* __restrict__ ovf_b,
                               ull* __restrict__ ovf_e,
                               const float* __restrict__ x, const float* __restrict__ lin_W,
                               const float* __restrict__ lin_b, float* __restrict__ h0) {
    __shared__ ull ent[PT];               // 32 KB
    __shared__ unsigned short ebin[PT];   // 8 KB
    __shared__ int hist[NBINS];
    __shared__ int cur[NBINS];
    __shared__ int gdel[NBINS];
    __shared__ int sc[512];
    int t = threadIdx.x;
    if (blockIdx.x < NPART) {
        int e0 = blockIdx.x * PT;
        int n = N_EDGES - e0; if (n > PT) n = PT;
        for (int b = t; b < NBINS; b += 256) hist[b] = 0;
        __syncthreads();
        for (int k = t; k < n; k += 256) atomicAdd(&hist[dst[e0 + k] >> 8], 1);
        __syncthreads();
        sc[t] = (t < NBINS) ? hist[t] : 0;
        sc[t + 256] = (t + 256 < NBINS) ? hist[t + 256] : 0;
        __syncthreads();
        for (int off = 1; off < 512; off <<= 1) {
            int a0 = sc[t] + ((t >= off) ? sc[t - off] : 0);
            int a1 = sc[t + 256] + sc[t + 256 - off];
            __syncthreads();
            sc[t] = a0; sc[t + 256] = a1;
            __syncthreads();
        }
        for (int b = t; b < NBINS; b += 256) {
            int lb = sc[b] - hist[b];
            cur[b] = lb;
            int gb = atomicAdd(&gcnt[b], hist[b]);
            gdel[b] = gb - lb;
        }
        __syncthreads();
        for (int k = t; k < n; k += 256) {
            int i = e0 + k;
            int d = dst[i];
            uint aq = (uint)(attr[i] * A18); if (aq > 0x3FFFFu) aq = 0x3FFFFu;
            int bin = d >> 8;
            ull e = ((ull)(d & 255) << 56) | ((ull)i << 35) | ((ull)src[i] << 18) | aq;
            int p = atomicAdd(&cur[bin], 1);
            ent[p] = e;
            ebin[p] = (unsigned short)bin;
        }
        __syncthreads();
        for (int k = t; k < n; k += 256) {
            int b = ebin[k];
            int off = k + gdel[b];
            if (off < BCAP) bucket[(size_t)b * BCAP + off] = ent[k];
            else {
                int q = atomicAdd(&flags[1], 1);
                if (q < OVF_CAP) { ovf_b[q] = b; ovf_e[q] = ent[k]; }
            }
        }
        return;
    }
    // ---- fused GEMM blocks: h0 = x @ lin_W + lin_b
    float* xs = (float*)ent;
    int lane = t & 63, w = t >> 6;
    int base = (blockIdx.x - NPART) * 32;
    const float4* Xv = (const float4*)(x + (size_t)base * 64);
    float4* xsv = (float4*)xs;
    xsv[t] = Xv[t];
    xsv[t + 256] = Xv[t + 256];
    float wc[64];
    #pragma unroll
    for (int k = 0; k < 64; ++k) wc[k] = lin_W[k * 64 + lane];
    __syncthreads();
    float bval = lin_b[lane];
    for (int rr = 0; rr < 8; ++rr) {
        int rl = w * 8 + rr;
        float acc = bval;
        #pragma unroll
        for (int k = 0; k < 64; ++k) acc = fmaf(xs[rl * 64 + k], wc[k], acc);
        h0[(size_t)(base + rl) * 64 + lane] = acc;
    }
}

// ---------------- finalize+reorder: node-sort entries -> csr2 (coalesced),
// per-node start/len, deg->dinv, last-write-winner attr, zero-indeg marks.
__launch_bounds__(256)
__global__ void finalize_reorder(const ull* __restrict__ bucket, const int* __restrict__ gcnt,
                                 const int* __restrict__ ovf_b, const ull* __restrict__ ovf_e,
                                 int* __restrict__ flags, uint* __restrict__ zbitmap,
                                 float* __restrict__ dinv, float* __restrict__ wa,
                                 ull* __restrict__ csr2, int* __restrict__ startv,
                                 int* __restrict__ lenv) {
    __shared__ ull ent[BCAP];        // 36.8 KB
    __shared__ int cnt[256];
    __shared__ int sc[256];
    __shared__ int cur[256];
    __shared__ int cbase[257];
    int t = threadIdx.x, b = blockIdx.x;
    int len = gcnt[b], blen = len < BCAP ? len : BCAP;
    const ull* bb = bucket + (size_t)b * BCAP;
    cnt[t] = 0;
    __syncthreads();
    ull r[18];
    #pragma unroll
    for (int k = 0; k < 18; ++k) {
        int j = k * 256 + t;
        r[k] = 0;
        if (j < blen) {
            ull e = bb[j];
            r[k] = e;
            atomicAdd(&cnt[(int)(e >> 56)], 1);
        }
    }
    __syncthreads();
    sc[t] = cnt[t];
    __syncthreads();
    for (int off = 1; off < 256; off <<= 1) {
        int a = sc[t] + ((t >= off) ? sc[t - off] : 0);
        __syncthreads();
        sc[t] = a;
        __syncthreads();
    }
    cbase[t + 1] = sc[t];
    if (t == 0) cbase[0] = 0;
    cur[t] = sc[t] - cnt[t];
    __syncthreads();
    #pragma unroll
    for (int k = 0; k < 18; ++k) {
        int j = k * 256 + t;
        if (j < blen) {
            ull e = r[k];
            int p = atomicAdd(&cur[(int)(e >> 56)], 1);
            ent[p] = e;
        }
    }
    __syncthreads();
    size_t base = (size_t)b * BCAP;
    for (int k = t; k < blen; k += 256) {
        ull e = ent[k];
        csr2[base + k] = (((ull)(e & 0x3FFFFull)) << 32) | ((e >> 18) & 0x1FFFFull);
    }
    int j0 = cbase[t], j1 = cbase[t + 1];
    float sum = 0.0f; uint winx = 0, wat = 0;
    for (int j = j0; j < j1; ++j) {
        ull e = ent[j];
        uint aq = (uint)(e & 0x3FFFFull);
        sum += (float)aq * A18_INV;
        uint ei = (uint)((e >> 35) & 0x1FFFFFull) + 1u;
        if (ei > winx) { winx = ei; wat = aq; }
    }
    if (len > BCAP) {                      // overflow (practically never)
        int oc = flags[1]; if (oc > OVF_CAP) oc = OVF_CAP;
        for (int q = 0; q < oc; ++q) {
            if (ovf_b[q] != b) continue;
            ull e = ovf_e[q];
            if ((int)(e >> 56) != t) continue;
            uint aq = (uint)(e & 0x3FFFFull);
            sum += (float)aq * A18_INV;
            uint ei = (uint)((e >> 35) & 0x1FFFFFull) + 1u;
            if (ei > winx) { winx = ei; wat = aq; }
        }
    }
    int v = b * 256 + t;
    if (v < N_NODES) {
        dinv[v] = rsqrtf(1.0f + sum);
        startv[v] = (int)(base + j0);
        lenv[v] = j1 - j0;
        if (winx > 0) {
            wa[v] = (float)wat * A18_INV;
        } else {
            wa[v] = -1.0f;
            atomicOr(&zbitmap[v >> 5], 1u << (v & 31));
            flags[0] = 1;
        }
    }
}

// ---------------- fixup: src-side winner for zero-in-degree nodes (early-exit)
__global__ void fixup_scan(const int* __restrict__ src, const int* __restrict__ flags,
                           const uint* __restrict__ zbitmap, int* __restrict__ win) {
    if (flags[0] == 0) return;
    int i = blockIdx.x * 256 + threadIdx.x;
    int s = src[i];
    if ((zbitmap[s >> 5] >> (s & 31)) & 1u) atomicMax(&win[s], i);
}

__global__ void fixup_apply(const int* __restrict__ flags, const uint* __restrict__ zbitmap,
                            const int* __restrict__ win, const float* __restrict__ attr,
                            float* __restrict__ wa) {
    if (flags[0] == 0) return;
    int v = blockIdx.x * 256 + threadIdx.x;
    if (v >= N_NODES) return;
    if (((zbitmap[v >> 5] >> (v & 31)) & 1u) && win[v] >= 0) wa[v] = attr[win[v]];
}

// ---------------- layer-0 GEMM + fused nrm-precompute blocks
// nrm blocks: csr2 entry (aq<<32|src) -> (f32(aq*dinv[src])<<32|src)
__launch_bounds__(256)
__global__ void gemm_l0_nrm(const float* __restrict__ h0, const float* __restrict__ W,
                            const float* __restrict__ wa, const float* __restrict__ ew,
                            const float* __restrict__ eb, __half* __restrict__ xw16,
                            ull* __restrict__ csr2, const int* __restrict__ gcnt,
                            const float* __restrict__ dinv) {
    __shared__ float xs[2048];
    int t = threadIdx.x;
    if (blockIdx.x < NBINS) {
        int b = blockIdx.x;
        int len = gcnt[b], blen = len < BCAP ? len : BCAP;
        ull* c = csr2 + (size_t)b * BCAP;
        for (int k = t; k < blen; k += 256) {
            ull pk = c[k];
            uint s = (uint)pk;
            float np = (float)(uint)(pk >> 32) * A18_INV * dinv[s];
            c[k] = ((ull)__float_as_uint(np) << 32) | s;
        }
        return;
    }
    int lane = t & 63, w = t >> 6;
    int base = (blockIdx.x - NBINS) * 32;
    const float4* Hv = (const float4*)(h0 + (size_t)base * 64);
    #pragma unroll
    for (int q = 0; q < 2; ++q) {
        int idx = t + q * 256;
        int rl = idx >> 4, f0 = (idx & 15) * 4;
        float4 v = Hv[idx];
        float wav = wa[base + rl];
        if (wav >= 0.0f) {
            v.x = fmaxf(fmaf(wav, ew[f0 + 0], v.x + eb[f0 + 0]), 0.0f);
            v.y = fmaxf(fmaf(wav, ew[f0 + 1], v.y + eb[f0 + 1]), 0.0f);
            v.z = fmaxf(fmaf(wav, ew[f0 + 2], v.z + eb[f0 + 2]), 0.0f);
            v.w = fmaxf(fmaf(wav, ew[f0 + 3], v.w + eb[f0 + 3]), 0.0f);
        }
        ((float4*)xs)[idx] = v;
    }
    float wc[64];
    #pragma unroll
    for (int k = 0; k < 64; ++k) wc[k] = W[k * 64 + lane];
    __syncthreads();
    for (int rr = 0; rr < 8; ++rr) {
        int rl = w * 8 + rr;
        float acc = 0.0f;
        #pragma unroll
        for (int k = 0; k < 64; ++k) acc = fmaf(xs[rl * 64 + k], wc[k], acc);
        xw16[(size_t)(base + rl) * 64 + lane] = __float2half(acc);
    }
}

// ---------------- layer-1 GEMM: stage agg0 + BN0 + relu, write out[:,0:64], fp16 xw
__launch_bounds__(256)
__global__ void gemm_l1(const float* __restrict__ agg, const float* __restrict__ bnacc,
                        const float* __restrict__ gamma, const float* __restrict__ beta,
                        const float* __restrict__ W, float* __restrict__ out,
                        __half* __restrict__ xw16) {
    __shared__ float xs[2048];
    int t = threadIdx.x, lane = t & 63, w = t >> 6;
    int base = blockIdx.x * 32;
    const float4* Av = (const float4*)(agg + (size_t)base * 64);
    const float invN = 1.0f / (float)N_NODES;
    #pragma unroll
    for (int q = 0; q < 2; ++q) {
        int idx = t + q * 256;
        int rl = idx >> 4, f0 = (idx & 15) * 4;
        float4 v = Av[idx];
        float vv[4] = {v.x, v.y, v.z, v.w};
        #pragma unroll
        for (int c = 0; c < 4; ++c) {
            int f = f0 + c;
            float mean = bnacc[f] * invN;
            float var = bnacc[64 + f] * invN - mean * mean;
            float scl = gamma[f] * rsqrtf(var + BN_EPS);
            float bs = beta[f] - mean * scl;
            vv[c] = fmaxf(fmaf(vv[c], scl, bs), 0.0f);
        }
        float4 r = {vv[0], vv[1], vv[2], vv[3]};
        ((float4*)xs)[idx] = r;
        *(float4*)(out + (size_t)(base + rl) * 128 + f0) = r;   // out[:, 0:64]
    }
    float wc[64];
    #pragma unroll
    for (int k = 0; k < 64; ++k) wc[k] = W[k * 64 + lane];
    __syncthreads();
    for (int rr = 0; rr < 8; ++rr) {
        int rl = w * 8 + rr;
        float acc = 0.0f;
        #pragma unroll
        for (int k = 0; k < 64; ++k) acc = fmaf(xs[rl * 64 + k], wc[k], acc);
        xw16[(size_t)(base + rl) * 64 + lane] = __float2half(acc);
    }
}

// ---------------- gather v6 ("gather16a"): 4 nodes per wave; lane=(ng:2|fl:4);
// 8B/lane row loads; CSR chunks of 16/node. The 16 row loads are issued as
// inline-asm global_load_dwordx2 (saddr form, 32-bit voffset) followed by ONE
// inline-asm s_waitcnt vmcnt(0) that ties all 16 payload registers through it
// ("+v") — SSA dataflow forces loads -> wait -> use, so the compiler CANNOT
// serialize to MLP=1 (R1/R2 failure mode: pre-RA scheduler sank each load to
// its use regardless of the VGPR budget). Zero-padded tails read row 0.
// 6250 blocks * 16 nodes = 100000 exact.
__launch_bounds__(256, 2)
__global__ void gather16(const __half* __restrict__ xw16, const ull* __restrict__ csr2,
                         const int* __restrict__ startv, const int* __restrict__ lenv,
                         const float* __restrict__ dinv, const int* __restrict__ gcnt,
                         const int* __restrict__ flags, const int* __restrict__ ovf_b,
                         const ull* __restrict__ ovf_e,
                         const float* __restrict__ convb, float* __restrict__ agg,
                         float* __restrict__ bnacc) {
    __shared__ float reds[4][64];
    __shared__ float redq[4][64];
    int t = threadIdx.x, lane = t & 63, w = t >> 6;
    int ng = lane >> 4, fl = lane & 15, f0 = fl * 4, ngb = ng << 4;
    uint boff = (uint)(f0 * 2);                      // byte offset within 128B row
    int v = blockIdx.x * 16 + w * 4 + ng;            // < 100000 always
    float dv = dinv[v];
    int sb = startv[v], ln = lenv[v];
    // self-loop term: w2 * xw[v]
    float2 raw = *(const float2*)(xw16 + (size_t)v * 64 + f0);
    float2 xv01 = __half22float2(*(__half2*)&raw.x);
    float2 xv23 = __half22float2(*(__half2*)&raw.y);
    float w2 = dv * dv;
    float a0 = w2 * xv01.x, a1 = w2 * xv01.y, a2 = w2 * xv23.x, a3 = w2 * xv23.y;
    float b0 = 0.f, b1 = 0.f, b2 = 0.f, b3 = 0.f;
    // first chunk's entries (zero-padded beyond ln)
    ull pk = (fl < ln) ? csr2[sb + fl] : 0ull;
    for (int c0 = 0; c0 < ln; c0 += 16) {
        ull pkc = pk;
        int rem = ln - c0 - 16;
        pk = (fl < rem) ? csr2[sb + c0 + 16 + fl] : 0ull;   // prefetch next chunk
        float nr[16];
        uint2v rw[16];
        #pragma unroll
        for (int j = 0; j < 16; ++j) {
            ull pj = __shfl(pkc, ngb + j, 64);
            nr[j] = __uint_as_float((uint)(pj >> 32)) * dv;
            uint off = (uint)pj * 128u + boff;
            asm volatile("global_load_dwordx2 %0, %1, %2"
                         : "=v"(rw[j]) : "v"(off), "s"(xw16));
        }
        asm volatile("s_waitcnt vmcnt(0)"
                     : "+v"(rw[0]), "+v"(rw[1]), "+v"(rw[2]), "+v"(rw[3]),
                       "+v"(rw[4]), "+v"(rw[5]), "+v"(rw[6]), "+v"(rw[7]),
                       "+v"(rw[8]), "+v"(rw[9]), "+v"(rw[10]), "+v"(rw[11]),
                       "+v"(rw[12]), "+v"(rw[13]), "+v"(rw[14]), "+v"(rw[15])
                     :: "memory");
        __builtin_amdgcn_sched_barrier(0);
        #pragma unroll
        for (int j = 0; j < 16; j += 2) {
            uint A0 = rw[j].x, A1 = rw[j].y, B0 = rw[j + 1].x, B1 = rw[j + 1].y;
            float2 xA01 = __half22float2(*(__half2*)&A0);
            float2 xA23 = __half22float2(*(__half2*)&A1);
            float2 xB01 = __half22float2(*(__half2*)&B0);
            float2 xB23 = __half22float2(*(__half2*)&B1);
            a0 = fmaf(nr[j], xA01.x, a0); a1 = fmaf(nr[j], xA01.y, a1);
            a2 = fmaf(nr[j], xA23.x, a2); a3 = fmaf(nr[j], xA23.y, a3);
            b0 = fmaf(nr[j + 1], xB01.x, b0); b1 = fmaf(nr[j + 1], xB01.y, b1);
            b2 = fmaf(nr[j + 1], xB23.x, b2); b3 = fmaf(nr[j + 1], xB23.y, b3);
        }
    }
    float t0 = a0 + b0, t1 = a1 + b1, t2 = a2 + b2, t3 = a3 + b3;
    int ovfn = flags[1];
    if (ovfn > 0 && gcnt[v >> 8] > BCAP) {     // practically never
        int oc = ovfn; if (oc > OVF_CAP) oc = OVF_CAP;
        int ld = v & 255, b = v >> 8;
        for (int q = 0; q < oc; ++q) {
            if (ovf_b[q] != b) continue;
            ull e = ovf_e[q];
            if ((int)(e >> 56) != ld) continue;
            uint s = (uint)((e >> 18) & 0x1FFFFull);
            float nrx = (float)(uint)(e & 0x3FFFFull) * A18_INV * dinv[s] * dv;
            float2 rr = *(const float2*)(xw16 + (size_t)s * 64 + f0);
            float2 x01 = __half22float2(*(__half2*)&rr.x);
            float2 x23 = __half22float2(*(__half2*)&rr.y);
            t0 = fmaf(nrx, x01.x, t0); t1 = fmaf(nrx, x01.y, t1);
            t2 = fmaf(nrx, x23.x, t2); t3 = fmaf(nrx, x23.y, t3);
        }
    }
    // + conv_b, store agg, accumulate BN stats
    float4 cb = *(const float4*)(convb + f0);
    t0 += cb.x; t1 += cb.y; t2 += cb.z; t3 += cb.w;
    *(float4*)(agg + (size_t)v * 64 + f0) = make_float4(t0, t1, t2, t3);
    float s0 = t0, s1 = t1, s2 = t2, s3 = t3;
    float q0 = t0 * t0, q1 = t1 * t1, q2 = t2 * t2, q3 = t3 * t3;
    // reduce across the 4 node-groups (lanes fl, 16+fl, 32+fl, 48+fl)
    s0 += __shfl_xor(s0, 16, 64); s0 += __shfl_xor(s0, 32, 64);
    s1 += __shfl_xor(s1, 16, 64); s1 += __shfl_xor(s1, 32, 64);
    s2 += __shfl_xor(s2, 16, 64); s2 += __shfl_xor(s2, 32, 64);
    s3 += __shfl_xor(s3, 16, 64); s3 += __shfl_xor(s3, 32, 64);
    q0 += __shfl_xor(q0, 16, 64); q0 += __shfl_xor(q0, 32, 64);
    q1 += __shfl_xor(q1, 16, 64); q1 += __shfl_xor(q1, 32, 64);
    q2 += __shfl_xor(q2, 16, 64); q2 += __shfl_xor(q2, 32, 64);
    q3 += __shfl_xor(q3, 16, 64); q3 += __shfl_xor(q3, 32, 64);
    if (ng == 0) {
        reds[w][f0] = s0; reds[w][f0 + 1] = s1; reds[w][f0 + 2] = s2; reds[w][f0 + 3] = s3;
        redq[w][f0] = q0; redq[w][f0 + 1] = q1; redq[w][f0 + 2] = q2; redq[w][f0 + 3] = q3;
    }
    __syncthreads();
    if (t < 64) {
        float ss = reds[0][t] + reds[1][t] + reds[2][t] + reds[3][t];
        float qq = redq[0][t] + redq[1][t] + redq[2][t] + redq[3][t];
        atomicAdd(&bnacc[t], ss);
        atomicAdd(&bnacc[64 + t], qq);
    }
}

// ---------------- final BN apply: out[:, 64:128]
__launch_bounds__(256)
__global__ void bn_final(const float* __restrict__ agg, const float* __restrict__ bnacc,
                         const float* __restrict__ gamma, const float* __restrict__ beta,
                         float* __restrict__ out) {
    int idx = blockIdx.x * 256 + threadIdx.x;
    int c = idx & 63, v = idx >> 6;
    const float invN = 1.0f / (float)N_NODES;
    float mean = bnacc[c] * invN;
    float var = bnacc[64 + c] * invN - mean * mean;
    float scl = gamma[c] * rsqrtf(var + BN_EPS);
    float bs = beta[c] - mean * scl;
    out[(size_t)v * 128 + 64 + c] = fmaf(agg[idx], scl, bs);
}

extern "C" void kernel_launch(void* const* d_in, const int* in_sizes, int n_in,
                              void* d_out, int out_size, void* d_ws, size_t ws_size,
                              hipStream_t stream) {
    const float* x      = (const float*)d_in[0];
    const int*   eidx   = (const int*)d_in[1];
    const float* attr   = (const float*)d_in[2];
    const float* lin_W  = (const float*)d_in[3];
    const float* lin_b  = (const float*)d_in[4];
    const float* eenc_w = (const float*)d_in[5];
    const float* eenc_b = (const float*)d_in[6];
    const float* conv_W = (const float*)d_in[7];
    const float* conv_b = (const float*)d_in[8];
    const float* gamma  = (const float*)d_in[9];
    const float* beta   = (const float*)d_in[10];
    float* out = (float*)d_out;

    const int* src = eidx;
    const int* dst = eidx + N_EDGES;

    // workspace carve (~70 MB)
    char* p = (char*)d_ws;
    ull* bucket = (ull*)p;   p += (size_t)NBINS * BCAP * 8;    // 14.4 MB
    ull* csr2   = (ull*)p;   p += (size_t)NBINS * BCAP * 8;    // 14.4 MB
    ull* ovf_e  = (ull*)p;   p += (size_t)OVF_CAP * 8;
    float* h0   = (float*)p; p += (size_t)N_NODES * 64 * 4;    // 25.6 MB (aliased: agg)
    __half* xw16 = (__half*)p; p += (size_t)N_NODES * 64 * 2;  // 12.8 MB
    float* dinv = (float*)p; p += (size_t)N_NODES * 4;
    float* wa   = (float*)p; p += (size_t)N_NODES * 4;
    int* win    = (int*)p;   p += (size_t)N_NODES * 4;
    int* startv = (int*)p;   p += (size_t)N_NODES * 4;
    int* lenv   = (int*)p;   p += (size_t)N_NODES * 4;
    int* ovf_b  = (int*)p;   p += (size_t)OVF_CAP * 4;
    int* gcnt   = (int*)p;   p += (NBINS + 1) * 4 + 20;
    uint* zbitmap = (uint*)p; p += 3125 * 4 + 12;
    int* flags  = (int*)p;   p += 64;
    float* bnacc = (float*)p; p += 256 * 4;                    // [2][128]
    float* agg = h0;   // h0 dead after gemm_l0_nrm

    init_kernel<<<NBLK_N, 256, 0, stream>>>(gcnt, win, zbitmap, flags, bnacc);
    partition_gemm<<<NPART + NBLK_G, 256, 0, stream>>>(src, dst, attr, bucket, gcnt,
                                                       flags, ovf_b, ovf_e,
                                                       x, lin_W, lin_b, h0);
    finalize_reorder<<<NBINS, 256, 0, stream>>>(bucket, gcnt, ovf_b, ovf_e,
                                                flags, zbitmap, dinv, wa,
                                                csr2, startv, lenv);
    fixup_scan<<<NBLK_E, 256, 0, stream>>>(src, flags, zbitmap, win);
    fixup_apply<<<NBLK_N, 256, 0, stream>>>(flags, zbitmap, win, attr, wa);

    gemm_l0_nrm<<<NBINS + NBLK_G, 256, 0, stream>>>(h0, conv_W, wa, eenc_w, eenc_b,
                                                    xw16, csr2, gcnt, dinv);
    gather16<<<6250, 256, 0, stream>>>(xw16, csr2, startv, lenv, dinv, gcnt,
                                       flags, ovf_b, ovf_e, conv_b, agg, bnacc);
    gemm_l1<<<NBLK_G, 256, 0, stream>>>(agg, bnacc, gamma, beta,
                                        conv_W + 64 * 64, out, xw16);
    gather16<<<6250, 256, 0, stream>>>(xw16, csr2, startv, lenv, dinv, gcnt,
                                       flags, ovf_b, ovf_e, conv_b + 64, agg, bnacc + 128);
    bn_final<<<25000, 256, 0, stream>>>(agg, bnacc + 128, gamma + 64, beta + 64, out);
}

// Round 4
// 465.518 us; speedup vs baseline: 1.4216x; 1.4177x over previous
//
#include <hip/hip_runtime.h>
#include <hip/hip_fp16.h>

#define N_NODES 100000
#define N_EDGES 1600000
#define BN_EPS 1e-5f
#define NBLK_E 6250      /* N_EDGES / 256 exact */
#define NBLK_G 3125      /* N_NODES / 32 exact */
#define NBLK_N 391       /* ceil(N_NODES/256) */
#define NBINS 391        /* buckets of 256 nodes */
#define BCAP 4608        /* entries per bucket (lambda=4096, +8 sigma) */
#define PT 4096          /* partition tile (edges per block) */
#define NPART 391        /* ceil(N_EDGES/PT) */
#define OVF_CAP 32768
#define A18 262144.0f
#define A18_INV 3.814697265625e-6f   /* 2^-18 */
typedef unsigned long long ull;
typedef unsigned int uint;

// bucket entry = local_d(8) | edge_idx(21) | src(17) | attr_q18(18)
// csr2 entry (after finalize) = attr_q18(high32) | src(low32)
// csr2 entry (after nrm blocks of gemm_l0_nrm) = f32(attr*dinv[src]) | src

// ---------------- init
__global__ void init_kernel(int* gcnt, int* win, uint* zbitmap, int* flags, float* bnacc) {
    int v = blockIdx.x * blockDim.x + threadIdx.x;
    if (v < N_NODES) win[v] = -1;
    if (v < NBINS) gcnt[v] = 0;
    if (v < 3125) zbitmap[v] = 0;
    if (v < 2) flags[v] = 0;          // [0]=zero-indeg-any  [1]=ovf_cnt
    if (v < 256) bnacc[v] = 0.0f;     // [2 layers][sum64|sq64]
}

// ---------------- partition (LDS-staged counting sort into 391 buckets) + fused h0 GEMM
__launch_bounds__(256)
__global__ void partition_gemm(const int* __restrict__ src, const int* __restrict__ dst,
                               const float* __restrict__ attr,
                               ull* __restrict__ bucket, int* __restrict__ gcnt,
                               int* __restrict__ flags, int* __restrict__ ovf_b,
                               ull* __restrict__ ovf_e,
                               const float* __restrict__ x, const float* __restrict__ lin_W,
                               const float* __restrict__ lin_b, float* __restrict__ h0) {
    __shared__ ull ent[PT];               // 32 KB
    __shared__ unsigned short ebin[PT];   // 8 KB
    __shared__ int hist[NBINS];
    __shared__ int cur[NBINS];
    __shared__ int gdel[NBINS];
    __shared__ int sc[512];
    int t = threadIdx.x;
    if (blockIdx.x < NPART) {
        int e0 = blockIdx.x * PT;
        int n = N_EDGES - e0; if (n > PT) n = PT;
        for (int b = t; b < NBINS; b += 256) hist[b] = 0;
        __syncthreads();
        for (int k = t; k < n; k += 256) atomicAdd(&hist[dst[e0 + k] >> 8], 1);
        __syncthreads();
        sc[t] = (t < NBINS) ? hist[t] : 0;
        sc[t + 256] = (t + 256 < NBINS) ? hist[t + 256] : 0;
        __syncthreads();
        for (int off = 1; off < 512; off <<= 1) {
            int a0 = sc[t] + ((t >= off) ? sc[t - off] : 0);
            int a1 = sc[t + 256] + sc[t + 256 - off];
            __syncthreads();
            sc[t] = a0; sc[t + 256] = a1;
            __syncthreads();
        }
        for (int b = t; b < NBINS; b += 256) {
            int lb = sc[b] - hist[b];
            cur[b] = lb;
            int gb = atomicAdd(&gcnt[b], hist[b]);
            gdel[b] = gb - lb;
        }
        __syncthreads();
        for (int k = t; k < n; k += 256) {
            int i = e0 + k;
            int d = dst[i];
            uint aq = (uint)(attr[i] * A18); if (aq > 0x3FFFFu) aq = 0x3FFFFu;
            int bin = d >> 8;
            ull e = ((ull)(d & 255) << 56) | ((ull)i << 35) | ((ull)src[i] << 18) | aq;
            int p = atomicAdd(&cur[bin], 1);
            ent[p] = e;
            ebin[p] = (unsigned short)bin;
        }
        __syncthreads();
        for (int k = t; k < n; k += 256) {
            int b = ebin[k];
            int off = k + gdel[b];
            if (off < BCAP) bucket[(size_t)b * BCAP + off] = ent[k];
            else {
                int q = atomicAdd(&flags[1], 1);
                if (q < OVF_CAP) { ovf_b[q] = b; ovf_e[q] = ent[k]; }
            }
        }
        return;
    }
    // ---- fused GEMM blocks: h0 = x @ lin_W + lin_b
    float* xs = (float*)ent;
    int lane = t & 63, w = t >> 6;
    int base = (blockIdx.x - NPART) * 32;
    const float4* Xv = (const float4*)(x + (size_t)base * 64);
    float4* xsv = (float4*)xs;
    xsv[t] = Xv[t];
    xsv[t + 256] = Xv[t + 256];
    float wc[64];
    #pragma unroll
    for (int k = 0; k < 64; ++k) wc[k] = lin_W[k * 64 + lane];
    __syncthreads();
    float bval = lin_b[lane];
    for (int rr = 0; rr < 8; ++rr) {
        int rl = w * 8 + rr;
        float acc = bval;
        #pragma unroll
        for (int k = 0; k < 64; ++k) acc = fmaf(xs[rl * 64 + k], wc[k], acc);
        h0[(size_t)(base + rl) * 64 + lane] = acc;
    }
}

// ---------------- finalize+reorder: node-sort entries -> csr2 (coalesced),
// per-node start/len, deg->dinv, last-write-winner attr, zero-indeg marks.
__launch_bounds__(256)
__global__ void finalize_reorder(const ull* __restrict__ bucket, const int* __restrict__ gcnt,
                                 const int* __restrict__ ovf_b, const ull* __restrict__ ovf_e,
                                 int* __restrict__ flags, uint* __restrict__ zbitmap,
                                 float* __restrict__ dinv, float* __restrict__ wa,
                                 ull* __restrict__ csr2, int* __restrict__ startv,
                                 int* __restrict__ lenv) {
    __shared__ ull ent[BCAP];        // 36.8 KB
    __shared__ int cnt[256];
    __shared__ int sc[256];
    __shared__ int cur[256];
    __shared__ int cbase[257];
    int t = threadIdx.x, b = blockIdx.x;
    int len = gcnt[b], blen = len < BCAP ? len : BCAP;
    const ull* bb = bucket + (size_t)b * BCAP;
    cnt[t] = 0;
    __syncthreads();
    ull r[18];
    #pragma unroll
    for (int k = 0; k < 18; ++k) {
        int j = k * 256 + t;
        r[k] = 0;
        if (j < blen) {
            ull e = bb[j];
            r[k] = e;
            atomicAdd(&cnt[(int)(e >> 56)], 1);
        }
    }
    __syncthreads();
    sc[t] = cnt[t];
    __syncthreads();
    for (int off = 1; off < 256; off <<= 1) {
        int a = sc[t] + ((t >= off) ? sc[t - off] : 0);
        __syncthreads();
        sc[t] = a;
        __syncthreads();
    }
    cbase[t + 1] = sc[t];
    if (t == 0) cbase[0] = 0;
    cur[t] = sc[t] - cnt[t];
    __syncthreads();
    #pragma unroll
    for (int k = 0; k < 18; ++k) {
        int j = k * 256 + t;
        if (j < blen) {
            ull e = r[k];
            int p = atomicAdd(&cur[(int)(e >> 56)], 1);
            ent[p] = e;
        }
    }
    __syncthreads();
    size_t base = (size_t)b * BCAP;
    for (int k = t; k < blen; k += 256) {
        ull e = ent[k];
        csr2[base + k] = (((ull)(e & 0x3FFFFull)) << 32) | ((e >> 18) & 0x1FFFFull);
    }
    int j0 = cbase[t], j1 = cbase[t + 1];
    float sum = 0.0f; uint winx = 0, wat = 0;
    for (int j = j0; j < j1; ++j) {
        ull e = ent[j];
        uint aq = (uint)(e & 0x3FFFFull);
        sum += (float)aq * A18_INV;
        uint ei = (uint)((e >> 35) & 0x1FFFFFull) + 1u;
        if (ei > winx) { winx = ei; wat = aq; }
    }
    if (len > BCAP) {                      // overflow (practically never)
        int oc = flags[1]; if (oc > OVF_CAP) oc = OVF_CAP;
        for (int q = 0; q < oc; ++q) {
            if (ovf_b[q] != b) continue;
            ull e = ovf_e[q];
            if ((int)(e >> 56) != t) continue;
            uint aq = (uint)(e & 0x3FFFFull);
            sum += (float)aq * A18_INV;
            uint ei = (uint)((e >> 35) & 0x1FFFFFull) + 1u;
            if (ei > winx) { winx = ei; wat = aq; }
        }
    }
    int v = b * 256 + t;
    if (v < N_NODES) {
        dinv[v] = rsqrtf(1.0f + sum);
        startv[v] = (int)(base + j0);
        lenv[v] = j1 - j0;
        if (winx > 0) {
            wa[v] = (float)wat * A18_INV;
        } else {
            wa[v] = -1.0f;
            atomicOr(&zbitmap[v >> 5], 1u << (v & 31));
            flags[0] = 1;
        }
    }
}

// ---------------- fixup: src-side winner for zero-in-degree nodes (early-exit)
__global__ void fixup_scan(const int* __restrict__ src, const int* __restrict__ flags,
                           const uint* __restrict__ zbitmap, int* __restrict__ win) {
    if (flags[0] == 0) return;
    int i = blockIdx.x * 256 + threadIdx.x;
    int s = src[i];
    if ((zbitmap[s >> 5] >> (s & 31)) & 1u) atomicMax(&win[s], i);
}

__global__ void fixup_apply(const int* __restrict__ flags, const uint* __restrict__ zbitmap,
                            const int* __restrict__ win, const float* __restrict__ attr,
                            float* __restrict__ wa) {
    if (flags[0] == 0) return;
    int v = blockIdx.x * 256 + threadIdx.x;
    if (v >= N_NODES) return;
    if (((zbitmap[v >> 5] >> (v & 31)) & 1u) && win[v] >= 0) wa[v] = attr[win[v]];
}

// ---------------- layer-0 GEMM + fused nrm-precompute blocks
// nrm blocks: csr2 entry (aq<<32|src) -> (f32(aq*dinv[src])<<32|src)
__launch_bounds__(256)
__global__ void gemm_l0_nrm(const float* __restrict__ h0, const float* __restrict__ W,
                            const float* __restrict__ wa, const float* __restrict__ ew,
                            const float* __restrict__ eb, __half* __restrict__ xw16,
                            ull* __restrict__ csr2, const int* __restrict__ gcnt,
                            const float* __restrict__ dinv) {
    __shared__ float xs[2048];
    int t = threadIdx.x;
    if (blockIdx.x < NBINS) {
        int b = blockIdx.x;
        int len = gcnt[b], blen = len < BCAP ? len : BCAP;
        ull* c = csr2 + (size_t)b * BCAP;
        for (int k = t; k < blen; k += 256) {
            ull pk = c[k];
            uint s = (uint)pk;
            float np = (float)(uint)(pk >> 32) * A18_INV * dinv[s];
            c[k] = ((ull)__float_as_uint(np) << 32) | s;
        }
        return;
    }
    int lane = t & 63, w = t >> 6;
    int base = (blockIdx.x - NBINS) * 32;
    const float4* Hv = (const float4*)(h0 + (size_t)base * 64);
    #pragma unroll
    for (int q = 0; q < 2; ++q) {
        int idx = t + q * 256;
        int rl = idx >> 4, f0 = (idx & 15) * 4;
        float4 v = Hv[idx];
        float wav = wa[base + rl];
        if (wav >= 0.0f) {
            v.x = fmaxf(fmaf(wav, ew[f0 + 0], v.x + eb[f0 + 0]), 0.0f);
            v.y = fmaxf(fmaf(wav, ew[f0 + 1], v.y + eb[f0 + 1]), 0.0f);
            v.z = fmaxf(fmaf(wav, ew[f0 + 2], v.z + eb[f0 + 2]), 0.0f);
            v.w = fmaxf(fmaf(wav, ew[f0 + 3], v.w + eb[f0 + 3]), 0.0f);
        }
        ((float4*)xs)[idx] = v;
    }
    float wc[64];
    #pragma unroll
    for (int k = 0; k < 64; ++k) wc[k] = W[k * 64 + lane];
    __syncthreads();
    for (int rr = 0; rr < 8; ++rr) {
        int rl = w * 8 + rr;
        float acc = 0.0f;
        #pragma unroll
        for (int k = 0; k < 64; ++k) acc = fmaf(xs[rl * 64 + k], wc[k], acc);
        xw16[(size_t)(base + rl) * 64 + lane] = __float2half(acc);
    }
}

// ---------------- layer-1 GEMM: stage agg0 + BN0 + relu, write out[:,0:64], fp16 xw
__launch_bounds__(256)
__global__ void gemm_l1(const float* __restrict__ agg, const float* __restrict__ bnacc,
                        const float* __restrict__ gamma, const float* __restrict__ beta,
                        const float* __restrict__ W, float* __restrict__ out,
                        __half* __restrict__ xw16) {
    __shared__ float xs[2048];
    int t = threadIdx.x, lane = t & 63, w = t >> 6;
    int base = blockIdx.x * 32;
    const float4* Av = (const float4*)(agg + (size_t)base * 64);
    const float invN = 1.0f / (float)N_NODES;
    #pragma unroll
    for (int q = 0; q < 2; ++q) {
        int idx = t + q * 256;
        int rl = idx >> 4, f0 = (idx & 15) * 4;
        float4 v = Av[idx];
        float vv[4] = {v.x, v.y, v.z, v.w};
        #pragma unroll
        for (int c = 0; c < 4; ++c) {
            int f = f0 + c;
            float mean = bnacc[f] * invN;
            float var = bnacc[64 + f] * invN - mean * mean;
            float scl = gamma[f] * rsqrtf(var + BN_EPS);
            float bs = beta[f] - mean * scl;
            vv[c] = fmaxf(fmaf(vv[c], scl, bs), 0.0f);
        }
        float4 r = {vv[0], vv[1], vv[2], vv[3]};
        ((float4*)xs)[idx] = r;
        *(float4*)(out + (size_t)(base + rl) * 128 + f0) = r;   // out[:, 0:64]
    }
    float wc[64];
    #pragma unroll
    for (int k = 0; k < 64; ++k) wc[k] = W[k * 64 + lane];
    __syncthreads();
    for (int rr = 0; rr < 8; ++rr) {
        int rl = w * 8 + rr;
        float acc = 0.0f;
        #pragma unroll
        for (int k = 0; k < 64; ++k) acc = fmaf(xs[rl * 64 + k], wc[k], acc);
        xw16[(size_t)(base + rl) * 64 + lane] = __float2half(acc);
    }
}

// ---------------- gather v7 ("gather_pair"): R0's proven gather4 shape (4 nodes
// per wave, 16 lanes/node, float2 row loads, 4 row loads in flight) but each
// lane-group owns TWO INDEPENDENT nodes vA in [0,50000) and vB = vA+50000.
// The two chains' csr2 loads and row loads interleave, overlapping their
// exposed latencies (~5 lat / 2 nodes instead of 5 / 1) without deepening any
// single chain past the proven MLP=4 (R1-R3 showed deep single-chain MLP is
// queue-limited / scheduler-sunk). Zero-padded tails: pk=0 -> nr=0, reads hot
// row 0. 3125 blocks * 16 slots * 2 nodes = 100000 exact.
__launch_bounds__(256, 4)
__global__ void gather_pair(const __half* __restrict__ xw16, const ull* __restrict__ csr2,
                            const int* __restrict__ startv, const int* __restrict__ lenv,
                            const float* __restrict__ dinv, const int* __restrict__ gcnt,
                            const int* __restrict__ flags, const int* __restrict__ ovf_b,
                            const ull* __restrict__ ovf_e,
                            const float* __restrict__ convb, float* __restrict__ agg,
                            float* __restrict__ bnacc) {
    __shared__ float reds[4][64];
    __shared__ float redq[4][64];
    int t = threadIdx.x, lane = t & 63, w = t >> 6;
    int ng = lane >> 4, fl = lane & 15, f0 = fl * 4, ngb = ng << 4;
    int vA = blockIdx.x * 16 + w * 4 + ng;      // [0, 50000)
    int vB = vA + 50000;                        // [50000, 100000)
    float dvA = dinv[vA], dvB = dinv[vB];
    int sbA = startv[vA], lnA = lenv[vA];
    int sbB = startv[vB], lnB = lenv[vB];
    // self-loop terms (two independent row loads, issued together)
    float2 rawA = *(const float2*)(xw16 + (size_t)vA * 64 + f0);
    float2 rawB = *(const float2*)(xw16 + (size_t)vB * 64 + f0);
    float2 xA01 = __half22float2(*(__half2*)&rawA.x);
    float2 xA23 = __half22float2(*(__half2*)&rawA.y);
    float2 xB01 = __half22float2(*(__half2*)&rawB.x);
    float2 xB23 = __half22float2(*(__half2*)&rawB.y);
    float w2A = dvA * dvA, w2B = dvB * dvB;
    float aA0 = w2A * xA01.x, aA1 = w2A * xA01.y, aA2 = w2A * xA23.x, aA3 = w2A * xA23.y;
    float bA0 = 0.f, bA1 = 0.f, bA2 = 0.f, bA3 = 0.f;
    float aB0 = w2B * xB01.x, aB1 = w2B * xB01.y, aB2 = w2B * xB23.x, aB3 = w2B * xB23.y;
    float bB0 = 0.f, bB1 = 0.f, bB2 = 0.f, bB3 = 0.f;
    int lnmax = lnA > lnB ? lnA : lnB;
    for (int c0 = 0; c0 < lnmax; c0 += 16) {
        ull pkA = (fl < lnA - c0) ? csr2[sbA + c0 + fl] : 0ull;
        ull pkB = (fl < lnB - c0) ? csr2[sbB + c0 + fl] : 0ull;
        #pragma unroll
        for (int j = 0; j < 16; j += 4) {
            ull pA0 = __shfl(pkA, ngb + j, 64);
            ull pA1 = __shfl(pkA, ngb + j + 1, 64);
            ull pA2 = __shfl(pkA, ngb + j + 2, 64);
            ull pA3 = __shfl(pkA, ngb + j + 3, 64);
            float2 rA0 = *(const float2*)(xw16 + (size_t)(uint)pA0 * 64 + f0);
            float2 rA1 = *(const float2*)(xw16 + (size_t)(uint)pA1 * 64 + f0);
            float2 rA2 = *(const float2*)(xw16 + (size_t)(uint)pA2 * 64 + f0);
            float2 rA3 = *(const float2*)(xw16 + (size_t)(uint)pA3 * 64 + f0);
            ull pB0 = __shfl(pkB, ngb + j, 64);
            ull pB1 = __shfl(pkB, ngb + j + 1, 64);
            ull pB2 = __shfl(pkB, ngb + j + 2, 64);
            ull pB3 = __shfl(pkB, ngb + j + 3, 64);
            float2 rB0 = *(const float2*)(xw16 + (size_t)(uint)pB0 * 64 + f0);
            float2 rB1 = *(const float2*)(xw16 + (size_t)(uint)pB1 * 64 + f0);
            float2 rB2 = *(const float2*)(xw16 + (size_t)(uint)pB2 * 64 + f0);
            float2 rB3 = *(const float2*)(xw16 + (size_t)(uint)pB3 * 64 + f0);
            float nA0 = __uint_as_float((uint)(pA0 >> 32)) * dvA;
            float nA1 = __uint_as_float((uint)(pA1 >> 32)) * dvA;
            float nA2 = __uint_as_float((uint)(pA2 >> 32)) * dvA;
            float nA3 = __uint_as_float((uint)(pA3 >> 32)) * dvA;
            float nB0 = __uint_as_float((uint)(pB0 >> 32)) * dvB;
            float nB1 = __uint_as_float((uint)(pB1 >> 32)) * dvB;
            float nB2 = __uint_as_float((uint)(pB2 >> 32)) * dvB;
            float nB3 = __uint_as_float((uint)(pB3 >> 32)) * dvB;
            float2 c01, c23;
            c01 = __half22float2(*(__half2*)&rA0.x); c23 = __half22float2(*(__half2*)&rA0.y);
            aA0 = fmaf(nA0, c01.x, aA0); aA1 = fmaf(nA0, c01.y, aA1);
            aA2 = fmaf(nA0, c23.x, aA2); aA3 = fmaf(nA0, c23.y, aA3);
            c01 = __half22float2(*(__half2*)&rA1.x); c23 = __half22float2(*(__half2*)&rA1.y);
            bA0 = fmaf(nA1, c01.x, bA0); bA1 = fmaf(nA1, c01.y, bA1);
            bA2 = fmaf(nA1, c23.x, bA2); bA3 = fmaf(nA1, c23.y, bA3);
            c01 = __half22float2(*(__half2*)&rA2.x); c23 = __half22float2(*(__half2*)&rA2.y);
            aA0 = fmaf(nA2, c01.x, aA0); aA1 = fmaf(nA2, c01.y, aA1);
            aA2 = fmaf(nA2, c23.x, aA2); aA3 = fmaf(nA2, c23.y, aA3);
            c01 = __half22float2(*(__half2*)&rA3.x); c23 = __half22float2(*(__half2*)&rA3.y);
            bA0 = fmaf(nA3, c01.x, bA0); bA1 = fmaf(nA3, c01.y, bA1);
            bA2 = fmaf(nA3, c23.x, bA2); bA3 = fmaf(nA3, c23.y, bA3);
            c01 = __half22float2(*(__half2*)&rB0.x); c23 = __half22float2(*(__half2*)&rB0.y);
            aB0 = fmaf(nB0, c01.x, aB0); aB1 = fmaf(nB0, c01.y, aB1);
            aB2 = fmaf(nB0, c23.x, aB2); aB3 = fmaf(nB0, c23.y, aB3);
            c01 = __half22float2(*(__half2*)&rB1.x); c23 = __half22float2(*(__half2*)&rB1.y);
            bB0 = fmaf(nB1, c01.x, bB0); bB1 = fmaf(nB1, c01.y, bB1);
            bB2 = fmaf(nB1, c23.x, bB2); bB3 = fmaf(nB1, c23.y, bB3);
            c01 = __half22float2(*(__half2*)&rB2.x); c23 = __half22float2(*(__half2*)&rB2.y);
            aB0 = fmaf(nB2, c01.x, aB0); aB1 = fmaf(nB2, c01.y, aB1);
            aB2 = fmaf(nB2, c23.x, aB2); aB3 = fmaf(nB2, c23.y, aB3);
            c01 = __half22float2(*(__half2*)&rB3.x); c23 = __half22float2(*(__half2*)&rB3.y);
            bB0 = fmaf(nB3, c01.x, bB0); bB1 = fmaf(nB3, c01.y, bB1);
            bB2 = fmaf(nB3, c23.x, bB2); bB3 = fmaf(nB3, c23.y, bB3);
        }
    }
    float tA0 = aA0 + bA0, tA1 = aA1 + bA1, tA2 = aA2 + bA2, tA3 = aA3 + bA3;
    float tB0 = aB0 + bB0, tB1 = aB1 + bB1, tB2 = aB2 + bB2, tB3 = aB3 + bB3;
    int ovfn = flags[1];
    if (ovfn > 0) {                            // practically never
        int oc = ovfn; if (oc > OVF_CAP) oc = OVF_CAP;
        if (gcnt[vA >> 8] > BCAP) {
            int ld = vA & 255, b = vA >> 8;
            for (int q = 0; q < oc; ++q) {
                if (ovf_b[q] != b) continue;
                ull e = ovf_e[q];
                if ((int)(e >> 56) != ld) continue;
                uint s = (uint)((e >> 18) & 0x1FFFFull);
                float nrx = (float)(uint)(e & 0x3FFFFull) * A18_INV * dinv[s] * dvA;
                float2 rr = *(const float2*)(xw16 + (size_t)s * 64 + f0);
                float2 x01 = __half22float2(*(__half2*)&rr.x);
                float2 x23 = __half22float2(*(__half2*)&rr.y);
                tA0 = fmaf(nrx, x01.x, tA0); tA1 = fmaf(nrx, x01.y, tA1);
                tA2 = fmaf(nrx, x23.x, tA2); tA3 = fmaf(nrx, x23.y, tA3);
            }
        }
        if (gcnt[vB >> 8] > BCAP) {
            int ld = vB & 255, b = vB >> 8;
            for (int q = 0; q < oc; ++q) {
                if (ovf_b[q] != b) continue;
                ull e = ovf_e[q];
                if ((int)(e >> 56) != ld) continue;
                uint s = (uint)((e >> 18) & 0x1FFFFull);
                float nrx = (float)(uint)(e & 0x3FFFFull) * A18_INV * dinv[s] * dvB;
                float2 rr = *(const float2*)(xw16 + (size_t)s * 64 + f0);
                float2 x01 = __half22float2(*(__half2*)&rr.x);
                float2 x23 = __half22float2(*(__half2*)&rr.y);
                tB0 = fmaf(nrx, x01.x, tB0); tB1 = fmaf(nrx, x01.y, tB1);
                tB2 = fmaf(nrx, x23.x, tB2); tB3 = fmaf(nrx, x23.y, tB3);
            }
        }
    }
    // + conv_b, store agg (both nodes), accumulate BN stats over both
    float4 cb = *(const float4*)(convb + f0);
    tA0 += cb.x; tA1 += cb.y; tA2 += cb.z; tA3 += cb.w;
    tB0 += cb.x; tB1 += cb.y; tB2 += cb.z; tB3 += cb.w;
    *(float4*)(agg + (size_t)vA * 64 + f0) = make_float4(tA0, tA1, tA2, tA3);
    *(float4*)(agg + (size_t)vB * 64 + f0) = make_float4(tB0, tB1, tB2, tB3);
    float s0 = tA0 + tB0, s1 = tA1 + tB1, s2 = tA2 + tB2, s3 = tA3 + tB3;
    float q0 = tA0 * tA0 + tB0 * tB0, q1 = tA1 * tA1 + tB1 * tB1;
    float q2 = tA2 * tA2 + tB2 * tB2, q3 = tA3 * tA3 + tB3 * tB3;
    // reduce across the 4 node-groups (lanes fl, 16+fl, 32+fl, 48+fl)
    s0 += __shfl_xor(s0, 16, 64); s0 += __shfl_xor(s0, 32, 64);
    s1 += __shfl_xor(s1, 16, 64); s1 += __shfl_xor(s1, 32, 64);
    s2 += __shfl_xor(s2, 16, 64); s2 += __shfl_xor(s2, 32, 64);
    s3 += __shfl_xor(s3, 16, 64); s3 += __shfl_xor(s3, 32, 64);
    q0 += __shfl_xor(q0, 16, 64); q0 += __shfl_xor(q0, 32, 64);
    q1 += __shfl_xor(q1, 16, 64); q1 += __shfl_xor(q1, 32, 64);
    q2 += __shfl_xor(q2, 16, 64); q2 += __shfl_xor(q2, 32, 64);
    q3 += __shfl_xor(q3, 16, 64); q3 += __shfl_xor(q3, 32, 64);
    if (ng == 0) {
        reds[w][f0] = s0; reds[w][f0 + 1] = s1; reds[w][f0 + 2] = s2; reds[w][f0 + 3] = s3;
        redq[w][f0] = q0; redq[w][f0 + 1] = q1; redq[w][f0 + 2] = q2; redq[w][f0 + 3] = q3;
    }
    __syncthreads();
    if (t < 64) {
        float ss = reds[0][t] + reds[1][t] + reds[2][t] + reds[3][t];
        float qq = redq[0][t] + redq[1][t] + redq[2][t] + redq[3][t];
        atomicAdd(&bnacc[t], ss);
        atomicAdd(&bnacc[64 + t], qq);
    }
}

// ---------------- final BN apply: out[:, 64:128]
__launch_bounds__(256)
__global__ void bn_final(const float* __restrict__ agg, const float* __restrict__ bnacc,
                         const float* __restrict__ gamma, const float* __restrict__ beta,
                         float* __restrict__ out) {
    int idx = blockIdx.x * 256 + threadIdx.x;
    int c = idx & 63, v = idx >> 6;
    const float invN = 1.0f / (float)N_NODES;
    float mean = bnacc[c] * invN;
    float var = bnacc[64 + c] * invN - mean * mean;
    float scl = gamma[c] * rsqrtf(var + BN_EPS);
    float bs = beta[c] - mean * scl;
    out[(size_t)v * 128 + 64 + c] = fmaf(agg[idx], scl, bs);
}

extern "C" void kernel_launch(void* const* d_in, const int* in_sizes, int n_in,
                              void* d_out, int out_size, void* d_ws, size_t ws_size,
                              hipStream_t stream) {
    const float* x      = (const float*)d_in[0];
    const int*   eidx   = (const int*)d_in[1];
    const float* attr   = (const float*)d_in[2];
    const float* lin_W  = (const float*)d_in[3];
    const float* lin_b  = (const float*)d_in[4];
    const float* eenc_w = (const float*)d_in[5];
    const float* eenc_b = (const float*)d_in[6];
    const float* conv_W = (const float*)d_in[7];
    const float* conv_b = (const float*)d_in[8];
    const float* gamma  = (const float*)d_in[9];
    const float* beta   = (const float*)d_in[10];
    float* out = (float*)d_out;

    const int* src = eidx;
    const int* dst = eidx + N_EDGES;

    // workspace carve (~70 MB)
    char* p = (char*)d_ws;
    ull* bucket = (ull*)p;   p += (size_t)NBINS * BCAP * 8;    // 14.4 MB
    ull* csr2   = (ull*)p;   p += (size_t)NBINS * BCAP * 8;    // 14.4 MB
    ull* ovf_e  = (ull*)p;   p += (size_t)OVF_CAP * 8;
    float* h0   = (float*)p; p += (size_t)N_NODES * 64 * 4;    // 25.6 MB (aliased: agg)
    __half* xw16 = (__half*)p; p += (size_t)N_NODES * 64 * 2;  // 12.8 MB
    float* dinv = (float*)p; p += (size_t)N_NODES * 4;
    float* wa   = (float*)p; p += (size_t)N_NODES * 4;
    int* win    = (int*)p;   p += (size_t)N_NODES * 4;
    int* startv = (int*)p;   p += (size_t)N_NODES * 4;
    int* lenv   = (int*)p;   p += (size_t)N_NODES * 4;
    int* ovf_b  = (int*)p;   p += (size_t)OVF_CAP * 4;
    int* gcnt   = (int*)p;   p += (NBINS + 1) * 4 + 20;
    uint* zbitmap = (uint*)p; p += 3125 * 4 + 12;
    int* flags  = (int*)p;   p += 64;
    float* bnacc = (float*)p; p += 256 * 4;                    // [2][128]
    float* agg = h0;   // h0 dead after gemm_l0_nrm

    init_kernel<<<NBLK_N, 256, 0, stream>>>(gcnt, win, zbitmap, flags, bnacc);
    partition_gemm<<<NPART + NBLK_G, 256, 0, stream>>>(src, dst, attr, bucket, gcnt,
                                                       flags, ovf_b, ovf_e,
                                                       x, lin_W, lin_b, h0);
    finalize_reorder<<<NBINS, 256, 0, stream>>>(bucket, gcnt, ovf_b, ovf_e,
                                                flags, zbitmap, dinv, wa,
                                                csr2, startv, lenv);
    fixup_scan<<<NBLK_E, 256, 0, stream>>>(src, flags, zbitmap, win);
    fixup_apply<<<NBLK_N, 256, 0, stream>>>(flags, zbitmap, win, attr, wa);

    gemm_l0_nrm<<<NBINS + NBLK_G, 256, 0, stream>>>(h0, conv_W, wa, eenc_w, eenc_b,
                                                    xw16, csr2, gcnt, dinv);
    gather_pair<<<NBLK_G, 256, 0, stream>>>(xw16, csr2, startv, lenv, dinv, gcnt,
                                            flags, ovf_b, ovf_e, conv_b, agg, bnacc);
    gemm_l1<<<NBLK_G, 256, 0, stream>>>(agg, bnacc, gamma, beta,
                                        conv_W + 64 * 64, out, xw16);
    gather_pair<<<NBLK_G, 256, 0, stream>>>(xw16, csr2, startv, lenv, dinv, gcnt,
                                            flags, ovf_b, ovf_e, conv_b + 64, agg, bnacc + 128);
    bn_final<<<25000, 256, 0, stream>>>(agg, bnacc + 128, gamma + 64, beta + 64, out);
}